// Round 14
// baseline (229.090 us; speedup 1.0000x reference)
//
#include <hip/hip_runtime.h>

// ---------------- constants ----------------
#define Bq 8
#define Tq 129
#define Sq 128
#define Hq 512
#define Nq 64
#define NLq 4
#define NEq 128
#define Vq 18

typedef unsigned short u16;
typedef unsigned int u32;
typedef __attribute__((ext_vector_type(8))) short short8v;   // 8 bf16 (4 VGPRs), MFMA A/B frag
typedef __attribute__((ext_vector_type(4))) float f32x4;     // MFMA C/D frag

__device__ __forceinline__ float gelu_f(float x) {
  return 0.5f * x * (1.0f + erff(x * 0.70710678118654752f));
}

__device__ __forceinline__ u16 f2b(float x) {   // f32 -> bf16, round-to-nearest-even
  union { float f; unsigned int u; } v; v.f = x;
  unsigned int r = v.u + 0x7FFFu + ((v.u >> 16) & 1u);
  return (u16)(r >> 16);
}

__device__ __forceinline__ float b2f_lo(u32 u) {
  union { unsigned int u; float f; } v; v.u = u << 16; return v.f;
}
__device__ __forceinline__ float b2f_hi(u32 u) {
  union { unsigned int u; float f; } v; v.u = u & 0xffff0000u; return v.f;
}

// ---------------- merged weight prep ----------------
// NOTE: B2t's ic index is PERMUTED to match conv1's packed-u32 output layout:
// o1 storage slot icS <-> real oc: real = (icS&1) ? 16+(icS>>1) : icS>>1.
__global__ __launch_bounds__(256) void prep_k(
    const float* __restrict__ enc_lw, const float* __restrict__ proj_w,
    const float* __restrict__ pre_w, const float* __restrict__ aft_w,
    const float* __restrict__ out_w,
    const float* __restrict__ w1, const float* __restrict__ w2,
    const float* __restrict__ w3,
    u16* __restrict__ Wt_enc, u16* __restrict__ Wt_proj, u16* __restrict__ Wt_pre,
    u16* __restrict__ Wt_aft, u16* __restrict__ Wt_out,
    u16* __restrict__ B1t, u16* __restrict__ B2t, u16* __restrict__ B3t) {
  __shared__ u16 T[64][65];
  int bid = blockIdx.x;
  if (bid >= 474) {  // conv permutes
    int i = (bid - 474) * 256 + threadIdx.x;
    if (i < 8192) {                       // conv1: [n=32][k=256], k=ic*64+ky*8+kx
      int n = i >> 8, k = i & 255;
      int ic = k >> 6, ky = (k >> 3) & 7, kx = k & 7;
      B1t[i] = f2b(w1[((n * 4 + ic) * 8 + ky) * 8 + kx]);
    } else if (i < 8192 + 32768) {        // conv2: [n=64][k=512], k=(ky*4+kx)*32+icS
      int j = i - 8192;
      int n = j >> 9, k = j & 511;
      int kyx = k >> 5, icS = k & 31, ky = kyx >> 2, kx = kyx & 3;
      int ic = (icS & 1) ? (16 + (icS >> 1)) : (icS >> 1);
      B2t[j] = f2b(w2[((n * 32 + ic) * 4 + ky) * 4 + kx]);
    } else if (i < 8192 + 32768 + 36864) { // conv3: [n=64][k=576], k=(ky*3+kx)*64+ic
      int j = i - 40960;
      int n = j / 576, k = j - n * 576;
      int ic = k & 63, kyx = k >> 6, ky = kyx / 3, kx = kyx % 3;
      B3t[j] = f2b(w3[((n * 64 + ic) * 3 + ky) * 3 + kx]);
    }
    return;
  }
  const float* src; u16* dst; int K, N, kt, nt, t;
  if (bid < 98)       { t = bid;       src = enc_lw; dst = Wt_enc;  K = 3136; N = 128; kt = t >> 1; nt = t & 1; }
  else if (bid < 146) { t = bid - 98;  src = proj_w; dst = Wt_proj; K = 384;  N = 512; kt = t >> 3; nt = t & 7; }
  else if (bid < 210) { t = bid - 146; src = pre_w;  dst = Wt_pre;  K = 512;  N = 512; kt = t >> 3; nt = t & 7; }
  else if (bid < 466) { t = bid - 210; int L = t >> 6; t &= 63;
                        src = aft_w + (size_t)L * 262144; dst = Wt_aft + (size_t)L * 262144;
                        K = 512; N = 512; kt = t >> 3; nt = t & 7; }
  else                { t = bid - 466; src = out_w;  dst = Wt_out;  K = 512;  N = 18;  kt = t;      nt = 0; }
  int k0 = kt * 64, n0 = nt * 64;
  #pragma unroll
  for (int it = 0; it < 16; it++) {
    int idx = it * 256 + threadIdx.x;
    int rr = idx >> 6, cc = idx & 63;
    float v = (n0 + cc < N) ? src[(size_t)(k0 + rr) * N + n0 + cc] : 0.f;
    T[cc][rr] = f2b(v);
  }
  __syncthreads();
  #pragma unroll
  for (int it = 0; it < 16; it++) {
    int idx = it * 256 + threadIdx.x;
    int rr = idx >> 6, cc = idx & 63;
    dst[(size_t)(n0 + rr) * K + k0 + cc] = T[rr][cc];
  }
}

// ---------------- conv1 MFMA, quarter-frame occupancy-first ----------------
// block = fr*4 + qt; qt covers oy in [5qt, 5qt+5), input rows [20qt, 20qt+24).
// LDS 16.1 KB (A only); B-fragments read from global (L1-resident 16 KB);
// split-issue staging. Packed u32 epilogue (oc r -> slot 2r, oc 16+r -> 2r+1).
__global__ __launch_bounds__(256) void conv1_mfma(const float* __restrict__ states,
    const u16* __restrict__ B1t, const float* __restrict__ bias, u16* __restrict__ out) {
  __shared__ u16 lds[4][2016];          // [ic][24 rows * 84]
  int blk = blockIdx.x;
  int fr = blk >> 2, qt = blk & 3;
  int b = fr >> 7, s = fr & 127;
  const float* in = states + (size_t)(b * Tq + s + 1) * 28224;
  int tid = threadIdx.x;
  float4 stg[8];
  #pragma unroll
  for (int it = 0; it < 8; it++) {
    int idx = tid + it * 256;
    if (idx < 2016) {
      int c = idx / 504, r2 = idx - c * 504;
      stg[it] = ((const float4*)(in + c * 7056))[420 * qt + r2];
    }
  }
  #pragma unroll
  for (int it = 0; it < 8; it++) {
    int idx = tid + it * 256;
    if (idx < 2016) {
      int c = idx / 504, r2 = idx - c * 504;
      ushort4 uv;
      uv.x = f2b(stg[it].x); uv.y = f2b(stg[it].y);
      uv.z = f2b(stg[it].z); uv.w = f2b(stg[it].w);
      *(ushort4*)&lds[c][r2 * 4] = uv;
    }
  }
  int lane = tid & 63, w = tid >> 6;
  int q = lane >> 4, r = lane & 15;
  float bn0 = bias[r], bn1 = bias[16 + r];
  __syncthreads();
  for (int mt = w; mt < 7; mt += 4) {
    int m = mt * 16 + r; if (m > 99) m = 99;
    int oyl = m / 20, ox = m % 20;
    f32x4 acc0 = {0.f, 0.f, 0.f, 0.f}, acc1 = {0.f, 0.f, 0.f, 0.f};
    #pragma unroll
    for (int ks = 0; ks < 8; ks++) {
      int k0 = ks * 32 + q * 8;
      int c = k0 >> 6, ky = (k0 >> 3) & 7;
      int ai = (oyl * 4 + ky) * 84 + ox * 4;
      ushort4 lo = *(const ushort4*)&lds[c][ai];
      ushort4 hi = *(const ushort4*)&lds[c][ai + 4];
      short8v av;
      av[0] = (short)lo.x; av[1] = (short)lo.y; av[2] = (short)lo.z; av[3] = (short)lo.w;
      av[4] = (short)hi.x; av[5] = (short)hi.y; av[6] = (short)hi.z; av[7] = (short)hi.w;
      short8v bv0 = *(const short8v*)(B1t + r * 256 + ks * 32 + q * 8);
      short8v bv1 = *(const short8v*)(B1t + (16 + r) * 256 + ks * 32 + q * 8);
      acc0 = __builtin_amdgcn_mfma_f32_16x16x32_bf16(av, bv0, acc0, 0, 0, 0);
      acc1 = __builtin_amdgcn_mfma_f32_16x16x32_bf16(av, bv1, acc1, 0, 0, 0);
    }
    #pragma unroll
    for (int reg = 0; reg < 4; reg++) {
      int pos = mt * 16 + q * 4 + reg;
      if (pos < 100) {
        int gp = qt * 100 + pos;
        u32 pk = (u32)f2b(fmaxf(acc0[reg] + bn0, 0.f)) |
                 ((u32)f2b(fmaxf(acc1[reg] + bn1, 0.f)) << 16);
        *(u32*)&out[(size_t)fr * 12800 + gp * 32 + 2 * r] = pk;
      }
    }
  }
}

// ---------------- fused conv2+conv3: o1 -> (LDS o2) -> x3b ----------------
__global__ __launch_bounds__(256) void conv23_mfma(const u16* __restrict__ o1,
    const u16* __restrict__ B2t, const u16* __restrict__ B3t,
    const float* __restrict__ b2, const float* __restrict__ b3,
    u16* __restrict__ x3b) {
  __shared__ u16 o1l[12800];   // [400 pos][32 slots]
  __shared__ u16 o2l[5184];    // [81 pos][64 oc]
  int fr = blockIdx.x;
  int tid = threadIdx.x;
  const short8v* src = (const short8v*)(o1 + (size_t)fr * 12800);
  short8v* dst = (short8v*)o1l;
  #pragma unroll
  for (int it = 0; it < 7; it++) {
    int idx = tid + it * 256;
    if (idx < 1600) dst[idx] = src[idx];
  }
  int lane = tid & 63, w = tid >> 6;
  int q = lane >> 4, r = lane & 15;
  int n = w * 16 + r;
  short8v bfr2[16];
  #pragma unroll
  for (int ks = 0; ks < 16; ks++)
    bfr2[ks] = *(const short8v*)(B2t + n * 512 + ks * 32 + q * 8);
  __syncthreads();
  // ---- conv2: M=81, N=64, K=512 -> o2l ----
  float bn2 = b2[n];
  #pragma unroll
  for (int mt = 0; mt < 6; mt++) {
    int m = mt * 16 + r; if (m > 80) m = 80;
    int oy = m / 9, ox = m % 9;
    f32x4 acc = {0.f, 0.f, 0.f, 0.f};
    #pragma unroll
    for (int ks = 0; ks < 16; ks++) {
      int ky = ks >> 2, kx = ks & 3;
      int ai = ((oy * 2 + ky) * 20 + ox * 2 + kx) * 32 + q * 8;
      short8v av = *(const short8v*)&o1l[ai];
      acc = __builtin_amdgcn_mfma_f32_16x16x32_bf16(av, bfr2[ks], acc, 0, 0, 0);
    }
    #pragma unroll
    for (int reg = 0; reg < 4; reg++) {
      int pos = mt * 16 + q * 4 + reg;
      if (pos < 81)
        o2l[pos * 64 + n] = f2b(fmaxf(acc[reg] + bn2, 0.f));
    }
  }
  short8v bfr3[18];
  #pragma unroll
  for (int ks = 0; ks < 18; ks++)
    bfr3[ks] = *(const short8v*)(B3t + n * 576 + ks * 32 + q * 8);
  __syncthreads();
  // ---- conv3: M=49, N=64, K=576 -> x3b (reference flatten order) ----
  float bn3 = b3[n];
  #pragma unroll
  for (int mt = 0; mt < 4; mt++) {
    int m = mt * 16 + r; if (m > 48) m = 48;
    int oy = m / 7, ox = m % 7;
    f32x4 acc = {0.f, 0.f, 0.f, 0.f};
    #pragma unroll
    for (int ks = 0; ks < 18; ks++) {
      int kyx = ks >> 1;
      int ky = kyx / 3, kx = kyx % 3;
      int ic0 = (ks & 1) * 32 + q * 8;
      int ai = ((oy + ky) * 9 + ox + kx) * 64 + ic0;
      short8v av = *(const short8v*)&o2l[ai];
      acc = __builtin_amdgcn_mfma_f32_16x16x32_bf16(av, bfr3[ks], acc, 0, 0, 0);
    }
    #pragma unroll
    for (int reg = 0; reg < 4; reg++) {
      int pos = mt * 16 + q * 4 + reg;
      if (pos < 49)
        x3b[(size_t)fr * 3136 + n * 49 + pos] = f2b(fmaxf(acc[reg] + bn3, 0.f));
    }
  }
}

// ---------------- bf16 MFMA GEMM: C = epi(A @ Wt^T + bias), BK=128 ----------------
template<bool AF32, int EPI, bool STATS>
__global__ __launch_bounds__(256) void mgemm(const void* __restrict__ Av,
    const u16* __restrict__ Wt, const float* __restrict__ bias,
    const float* __restrict__ res, void* __restrict__ Cv,
    float2* __restrict__ part, int M, int K, int N, int ldc) {
  __shared__ u16 As[4][64][40];
  __shared__ u16 Bs[4][64][40];
  int tid = threadIdx.x;
  int bn = blockIdx.x * 64, bm = blockIdx.y * 64;
  int lane = tid & 63, w = tid >> 6;
  int q = lane >> 4, r = lane & 15;
  int wm = (w >> 1) * 32, wn = (w & 1) * 32;
  int am = tid >> 2, ak0 = (tid & 3) * 8;
  f32x4 acc[2][2] = {};
  for (int k0 = 0; k0 < K; k0 += 128) {
    #pragma unroll
    for (int st = 0; st < 4; st++) {
      int kk = k0 + st * 32 + ak0;
      if constexpr (AF32) {
        const float* A = (const float*)Av;
        const float* src = A + (size_t)(bm + am) * K + kk;
        float4 v0 = *(const float4*)src;
        float4 v1 = *(const float4*)(src + 4);
        ushort4 lo, hi;
        lo.x = f2b(v0.x); lo.y = f2b(v0.y); lo.z = f2b(v0.z); lo.w = f2b(v0.w);
        hi.x = f2b(v1.x); hi.y = f2b(v1.y); hi.z = f2b(v1.z); hi.w = f2b(v1.w);
        *(ushort4*)&As[st][am][ak0] = lo;
        *(ushort4*)&As[st][am][ak0 + 4] = hi;
      } else {
        *(short8v*)&As[st][am][ak0] =
            *(const short8v*)((const u16*)Av + (size_t)(bm + am) * K + kk);
      }
      *(short8v*)&Bs[st][am][ak0] = *(const short8v*)(Wt + (size_t)(bn + am) * K + kk);
    }
    __syncthreads();
    #pragma unroll
    for (int st = 0; st < 4; st++) {
      short8v a0 = *(const short8v*)&As[st][wm + r][q * 8];
      short8v a1 = *(const short8v*)&As[st][wm + 16 + r][q * 8];
      short8v b0 = *(const short8v*)&Bs[st][wn + r][q * 8];
      short8v b1 = *(const short8v*)&Bs[st][wn + 16 + r][q * 8];
      acc[0][0] = __builtin_amdgcn_mfma_f32_16x16x32_bf16(a0, b0, acc[0][0], 0, 0, 0);
      acc[0][1] = __builtin_amdgcn_mfma_f32_16x16x32_bf16(a0, b1, acc[0][1], 0, 0, 0);
      acc[1][0] = __builtin_amdgcn_mfma_f32_16x16x32_bf16(a1, b0, acc[1][0], 0, 0, 0);
      acc[1][1] = __builtin_amdgcn_mfma_f32_16x16x32_bf16(a1, b1, acc[1][1], 0, 0, 0);
    }
    __syncthreads();
  }
  float yv[2][2][4];
  #pragma unroll
  for (int ms = 0; ms < 2; ms++) {
    #pragma unroll
    for (int ns = 0; ns < 2; ns++) {
      #pragma unroll
      for (int reg = 0; reg < 4; reg++) {
        int m = bm + wm + ms * 16 + q * 4 + reg;
        int n = bn + wn + ns * 16 + r;
        if (n < N) {
          float v = acc[ms][ns][reg] + (bias ? bias[n] : 0.f);
          if (EPI == 0) { ((float*)Cv)[(size_t)m * ldc + n] = v; yv[ms][ns][reg] = v; }
          if (EPI == 2) ((u16*)Cv)[(size_t)m * ldc + n] = f2b(gelu_f(v));
          if (EPI == 3) {
            float o = gelu_f(v) + res[(size_t)m * ldc + n];
            ((float*)Cv)[(size_t)m * ldc + n] = o; yv[ms][ns][reg] = o;
          }
        }
      }
    }
  }
  if constexpr (STATS) {
    #pragma unroll
    for (int ms = 0; ms < 2; ms++) {
      #pragma unroll
      for (int reg = 0; reg < 4; reg++) {
        float s = yv[ms][0][reg] + yv[ms][1][reg];
        float s2 = yv[ms][0][reg] * yv[ms][0][reg] + yv[ms][1][reg] * yv[ms][1][reg];
        #pragma unroll
        for (int o = 1; o <= 8; o <<= 1) {
          s += __shfl_xor(s, o);
          s2 += __shfl_xor(s2, o);
        }
        if (r == 0) {
          int m = bm + wm + ms * 16 + q * 4 + reg;
          part[(size_t)(blockIdx.x * 2 + (w & 1)) * 1024 + m] = make_float2(s, s2);
        }
      }
    }
  }
}

// ---------------- enc GEMM split-K ----------------
__global__ __launch_bounds__(256) void enc_gemm(const u16* __restrict__ A,
    const u16* __restrict__ Wt, float* __restrict__ Cp) {
  __shared__ u16 As[64][40];
  __shared__ u16 Bs[64][40];
  int tid = threadIdx.x;
  int bn = blockIdx.x * 64, bm = blockIdx.y * 64, kc = blockIdx.z;
  int lane = tid & 63, w = tid >> 6;
  int q = lane >> 4, r = lane & 15;
  int wm = (w >> 1) * 32, wn = (w & 1) * 32;
  int am = tid >> 2, ak = (tid & 3) * 8;
  f32x4 acc[2][2] = {};
  int kend = kc * 448 + 448;
  for (int k0 = kc * 448; k0 < kend; k0 += 32) {
    *(short8v*)&As[am][ak] = *(const short8v*)(A + (size_t)(bm + am) * 3136 + k0 + ak);
    *(short8v*)&Bs[am][ak] = *(const short8v*)(Wt + (size_t)(bn + am) * 3136 + k0 + ak);
    __syncthreads();
    short8v a0 = *(const short8v*)&As[wm + r][q * 8];
    short8v a1 = *(const short8v*)&As[wm + 16 + r][q * 8];
    short8v b0 = *(const short8v*)&Bs[wn + r][q * 8];
    short8v b1 = *(const short8v*)&Bs[wn + 16 + r][q * 8];
    acc[0][0] = __builtin_amdgcn_mfma_f32_16x16x32_bf16(a0, b0, acc[0][0], 0, 0, 0);
    acc[0][1] = __builtin_amdgcn_mfma_f32_16x16x32_bf16(a0, b1, acc[0][1], 0, 0, 0);
    acc[1][0] = __builtin_amdgcn_mfma_f32_16x16x32_bf16(a1, b0, acc[1][0], 0, 0, 0);
    acc[1][1] = __builtin_amdgcn_mfma_f32_16x16x32_bf16(a1, b1, acc[1][1], 0, 0, 0);
    __syncthreads();
  }
  #pragma unroll
  for (int ms = 0; ms < 2; ms++)
    #pragma unroll
    for (int ns = 0; ns < 2; ns++)
      #pragma unroll
      for (int reg = 0; reg < 4; reg++) {
        int m = bm + wm + ms * 16 + q * 4 + reg;
        int n = bn + wn + ns * 16 + r;
        Cp[(size_t)(kc * 1024 + m) * 128 + n] = acc[ms][ns][reg];
      }
}

// ---------------- enc reduce + embeddings -> uin (bf16) ----------------
__global__ __launch_bounds__(256) void embedred_k(const float* __restrict__ Cp,
    const float* __restrict__ enc_lb, const int* __restrict__ actions,
    const float* __restrict__ rtgs, const float* __restrict__ act_emb,
    const float* __restrict__ ret_w, const float* __restrict__ ret_b,
    u16* __restrict__ uin) {
  int f = blockIdx.x;
  int b = f >> 7, s = f & 127;
  int e = threadIdx.x;
  if (e < 128) {
    float sum = enc_lb[e];
    #pragma unroll
    for (int kc = 0; kc < 7; kc++) sum += Cp[(size_t)(kc * 1024 + f) * 128 + e];
    uin[(size_t)f * 384 + e] = f2b(tanhf(sum));
    uin[(size_t)f * 384 + 256 + e] =
        f2b(tanhf(fmaf(rtgs[b * Tq + s], ret_w[e], ret_b[e])));
  } else {
    int ee = e - 128;
    int a = actions[b * Tq + s];
    uin[(size_t)f * 384 + 128 + ee] = f2b(tanhf(act_emb[a * NEq + ee]));
  }
}

// ---------------- S4 kernel gen: Ktb[layer][l][h] bf16 ----------------
__global__ __launch_bounds__(64) void s4k_gen(const float* __restrict__ log_dt,
    const float* __restrict__ A_re, const float* __restrict__ A_im,
    const float* __restrict__ C_re, const float* __restrict__ C_im,
    u16* __restrict__ Ktb) {
  __shared__ float con[64][129];
  int lh = blockIdx.x;
  int n = threadIdx.x;
  float dt = expf(log_dt[lh]);
  float ar = A_re[(size_t)lh * Nq + n], ai = A_im[(size_t)lh * Nq + n];
  float al = dt * ar, be = dt * ai;
  float er = expf(al);
  float wr = er * cosf(be), wi = er * sinf(be);
  float zr = wr - 1.0f, zi = wi;
  float den = 1.0f / (ar * ar + ai * ai);
  float tr = (zr * ar + zi * ai) * den, ti = (zi * ar - zr * ai) * den;
  float Cr = C_re[(size_t)lh * Nq + n], Ci = C_im[(size_t)lh * Nq + n];
  float cr = Cr * tr - Ci * ti, ci = Cr * ti + Ci * tr;
  float curr = 1.0f, curi = 0.0f;
  for (int l = 0; l < Sq; l++) {
    con[n][l] = cr * curr - ci * curi;
    float nr = curr * wr - curi * wi;
    curi = curr * wi + curi * wr;
    curr = nr;
  }
  __syncthreads();
  int layer = lh >> 9, h = lh & 511;
  #pragma unroll
  for (int li = n; li < Sq; li += 64) {
    float s = 0.f;
    for (int j = 0; j < 64; j++) s += con[j][li];
    Ktb[((size_t)layer * Sq + li) * Hq + h] = f2b(2.0f * s);
  }
}

// ---------------- fused LN + causal seq conv + gelu -> bf16 ----------------
__global__ __launch_bounds__(256) void sconv_fused(const float* __restrict__ y,
    const float2* __restrict__ part, const float* __restrict__ g,
    const float* __restrict__ bta, const u16* __restrict__ Kt,
    const float* __restrict__ D, u16* __restrict__ cact) {
  __shared__ u32 P[16][140];
  __shared__ u32 KL[16][132];
  __shared__ float2 statl[128];
  int hc = blockIdx.x, b = blockIdx.y;
  int t = threadIdx.x;
  int h0 = hc * 32;
  if (t < 128) {
    float s = 0.f, s2 = 0.f;
    #pragma unroll
    for (int pc = 0; pc < 16; pc++) {
      float2 pp = part[(size_t)pc * 1024 + b * Sq + t];
      s += pp.x; s2 += pp.y;
    }
    float mu = s * (1.f / Hq);
    float var = s2 * (1.f / Hq) - mu * mu;
    statl[t] = make_float2(mu, rsqrtf(var + 1e-5f));
  }
  if (t < 16) {
    #pragma unroll
    for (int i = 0; i < 8; i++) P[t][i] = 0;
  }
  #pragma unroll
  for (int it = 0; it < 8; it++) {
    int idx = it * 256 + t;
    int p = idx & 15, j = idx >> 4;
    KL[p][j] = *(const u32*)(Kt + (size_t)j * Hq + h0 + 2 * p);
  }
  __syncthreads();
  #pragma unroll
  for (int it = 0; it < 8; it++) {
    int idx = it * 256 + t;
    int p = idx & 15, s = idx >> 4;
    int row = b * Sq + s;
    float2 v = *(const float2*)(y + (size_t)row * Hq + h0 + 2 * p);
    float2 st = statl[s];
    float2 gg = *(const float2*)(g + h0 + 2 * p);
    float2 bb = *(const float2*)(bta + h0 + 2 * p);
    float r0 = (v.x - st.x) * st.y * gg.x + bb.x;
    float r1 = (v.y - st.x) * st.y * gg.y + bb.y;
    P[p][8 + s] = (u32)f2b(r0) | ((u32)f2b(r1) << 16);
  }
  __syncthreads();
  int p = t & 15, sg = t >> 4;
  int s0 = sg * 8;
  float acc0[8], acc1[8];
  float2 d2 = *(const float2*)(D + h0 + 2 * p);
  #pragma unroll
  for (int k = 0; k < 8; k++) {
    u32 rv = P[p][8 + s0 + k];
    acc0[k] = d2.x * b2f_lo(rv);
    acc1[k] = d2.y * b2f_hi(rv);
  }
  for (int jb = 0; jb <= sg; jb++) {
    int base = (sg - jb) * 8;
    u32 wv[16], kv[8];
    *(uint4*)&wv[0]  = *(const uint4*)&P[p][base];
    *(uint4*)&wv[4]  = *(const uint4*)&P[p][base + 4];
    *(uint4*)&wv[8]  = *(const uint4*)&P[p][base + 8];
    *(uint4*)&wv[12] = *(const uint4*)&P[p][base + 12];
    *(uint4*)&kv[0]  = *(const uint4*)&KL[p][jb * 8];
    *(uint4*)&kv[4]  = *(const uint4*)&KL[p][jb * 8 + 4];
    float wlo[16], whi[16], klo[8], khi[8];
    #pragma unroll
    for (int i = 0; i < 16; i++) { wlo[i] = b2f_lo(wv[i]); whi[i] = b2f_hi(wv[i]); }
    #pragma unroll
    for (int i = 0; i < 8; i++) { klo[i] = b2f_lo(kv[i]); khi[i] = b2f_hi(kv[i]); }
    #pragma unroll
    for (int jo = 0; jo < 8; jo++)
      #pragma unroll
      for (int k = 0; k < 8; k++) {
        acc0[k] = fmaf(klo[jo], wlo[8 + k - jo], acc0[k]);
        acc1[k] = fmaf(khi[jo], whi[8 + k - jo], acc1[k]);
      }
  }
  #pragma unroll
  for (int k = 0; k < 8; k++) {
    int s = s0 + k;
    u32 outv = (u32)f2b(gelu_f(acc0[k])) | ((u32)f2b(gelu_f(acc1[k])) << 16);
    *(u32*)(cact + ((size_t)(b * Sq + s)) * Hq + h0 + 2 * p) = outv;
  }
}

// ---------------- host ----------------
extern "C" void kernel_launch(void* const* d_in, const int* in_sizes, int n_in,
                              void* d_out, int out_size, void* d_ws, size_t ws_size,
                              hipStream_t stream) {
  const float* states  = (const float*)d_in[0];
  const int*   actions = (const int*)  d_in[1];
  const float* rtgs    = (const float*)d_in[2];
  const float* enc_w1  = (const float*)d_in[3];
  const float* enc_b1  = (const float*)d_in[4];
  const float* enc_w2  = (const float*)d_in[5];
  const float* enc_b2  = (const float*)d_in[6];
  const float* enc_w3  = (const float*)d_in[7];
  const float* enc_b3  = (const float*)d_in[8];
  const float* enc_lw  = (const float*)d_in[9];
  const float* enc_lb  = (const float*)d_in[10];
  const float* ret_w   = (const float*)d_in[11];
  const float* ret_b   = (const float*)d_in[12];
  const float* act_emb = (const float*)d_in[13];
  const float* proj_w  = (const float*)d_in[14];
  const float* proj_b  = (const float*)d_in[15];
  const float* pre_w   = (const float*)d_in[16];
  const float* pre_b   = (const float*)d_in[17];
  const float* ln_g    = (const float*)d_in[18];
  const float* ln_b    = (const float*)d_in[19];
  const float* log_dt  = (const float*)d_in[20];
  const float* A_re    = (const float*)d_in[21];
  const float* A_im    = (const float*)d_in[22];
  const float* C_re    = (const float*)d_in[23];
  const float* C_im    = (const float*)d_in[24];
  const float* Dp      = (const float*)d_in[25];
  const float* aft_w   = (const float*)d_in[26];
  const float* aft_b   = (const float*)d_in[27];
  const float* out_w   = (const float*)d_in[28];

  // workspace layout (u16 units), all regions 16B aligned
  u16* Wt_enc  = (u16*)d_ws;            // 401,408
  u16* Wt_proj = Wt_enc + 401408;       // 196,608
  u16* Wt_pre  = Wt_proj + 196608;      // 262,144
  u16* Wt_aft  = Wt_pre + 262144;       // 1,048,576
  u16* Wt_out  = Wt_aft + 1048576;      // 32,768
  u16* B1t = Wt_out + 32768;            // 8,192
  u16* B2t = B1t + 8192;                // 32,768
  u16* B3t = B2t + 32768;               // 36,864
  u16* o1  = B3t + 36864;               // 13,107,200
  u16* x3b = o1 + 13107200;             // 3,211,264
  u16* uin = x3b + 3211264;             // 393,216
  u16* uact = uin + 393216;             // 524,288
  u16* cact = uact + 524288;            // 524,288
  u16* Ktb  = cact + 524288;            // 262,144
  float* y    = (float*)(Ktb + 262144); // 524,288 f32
  float* Cp   = y + 524288;             // 917,504 f32 (7*1024*128)
  float2* part = (float2*)(Cp + 917504);// 16*1024 float2

  prep_k<<<778, 256, 0, stream>>>(enc_lw, proj_w, pre_w, aft_w, out_w,
                                  enc_w1, enc_w2, enc_w3,
                                  Wt_enc, Wt_proj, Wt_pre, Wt_aft, Wt_out,
                                  B1t, B2t, B3t);
  conv1_mfma<<<4096, 256, 0, stream>>>(states, B1t, enc_b1, o1);
  conv23_mfma<<<1024, 256, 0, stream>>>(o1, B2t, B3t, enc_b2, enc_b3, x3b);
  enc_gemm<<<dim3(2, 16, 7), 256, 0, stream>>>(x3b, Wt_enc, Cp);
  embedred_k<<<1024, 256, 0, stream>>>(Cp, enc_lb, actions, rtgs, act_emb,
                                       ret_w, ret_b, uin);
  mgemm<false, 2, false><<<dim3(8, 16), 256, 0, stream>>>(uin, Wt_proj, proj_b,
      nullptr, uact, nullptr, 1024, 384, 512, 512);
  mgemm<false, 0, true><<<dim3(8, 16), 256, 0, stream>>>(uact, Wt_pre, pre_b,
      nullptr, y, part, 1024, 512, 512, 512);
  s4k_gen<<<2048, 64, 0, stream>>>(log_dt, A_re, A_im, C_re, C_im, Ktb);

  for (int i = 0; i < NLq; i++) {
    sconv_fused<<<dim3(16, 8), 256, 0, stream>>>(y, part, ln_g + i * Hq,
                                                 ln_b + i * Hq,
                                                 Ktb + (size_t)i * Sq * Hq,
                                                 Dp + i * Hq, cact);
    mgemm<false, 3, true><<<dim3(8, 16), 256, 0, stream>>>(cact,
        Wt_aft + (size_t)i * Hq * Hq, aft_b + i * Hq, y, y, part,
        1024, 512, 512, 512);
  }
  mgemm<true, 0, false><<<dim3(1, 16), 256, 0, stream>>>(y, Wt_out, nullptr,
      nullptr, (float*)d_out, nullptr, 1024, 512, Vq, Vq);
}

// Round 15
// 216.978 us; speedup vs baseline: 1.0558x; 1.0558x over previous
//
#include <hip/hip_runtime.h>

// ---------------- constants ----------------
#define Bq 8
#define Tq 129
#define Sq 128
#define Hq 512
#define Nq 64
#define NLq 4
#define NEq 128
#define Vq 18

typedef unsigned short u16;
typedef unsigned int u32;
typedef __attribute__((ext_vector_type(8))) short short8v;   // 8 bf16 (4 VGPRs), MFMA A/B frag
typedef __attribute__((ext_vector_type(4))) float f32x4;     // MFMA C/D frag

__device__ __forceinline__ float gelu_f(float x) {
  return 0.5f * x * (1.0f + erff(x * 0.70710678118654752f));
}

__device__ __forceinline__ u16 f2b(float x) {   // f32 -> bf16, round-to-nearest-even
  union { float f; unsigned int u; } v; v.f = x;
  unsigned int r = v.u + 0x7FFFu + ((v.u >> 16) & 1u);
  return (u16)(r >> 16);
}

__device__ __forceinline__ float b2f_lo(u32 u) {
  union { unsigned int u; float f; } v; v.u = u << 16; return v.f;
}
__device__ __forceinline__ float b2f_hi(u32 u) {
  union { unsigned int u; float f; } v; v.u = u & 0xffff0000u; return v.f;
}

// ---------------- merged weight prep ----------------
__global__ __launch_bounds__(256) void prep_k(
    const float* __restrict__ enc_lw, const float* __restrict__ proj_w,
    const float* __restrict__ pre_w, const float* __restrict__ aft_w,
    const float* __restrict__ out_w,
    const float* __restrict__ w1, const float* __restrict__ w2,
    const float* __restrict__ w3,
    u16* __restrict__ Wt_enc, u16* __restrict__ Wt_proj, u16* __restrict__ Wt_pre,
    u16* __restrict__ Wt_aft, u16* __restrict__ Wt_out,
    u16* __restrict__ B1t, u16* __restrict__ B2t, u16* __restrict__ B3t) {
  __shared__ u16 T[64][65];
  int bid = blockIdx.x;
  if (bid >= 474) {  // conv permutes
    int i = (bid - 474) * 256 + threadIdx.x;
    if (i < 8192) {                       // conv1: [n=32][k=256], k=ic*64+ky*8+kx
      int n = i >> 8, k = i & 255;
      int ic = k >> 6, ky = (k >> 3) & 7, kx = k & 7;
      B1t[i] = f2b(w1[((n * 4 + ic) * 8 + ky) * 8 + kx]);
    } else if (i < 8192 + 32768) {        // conv2: [n=64][k=512], k=(ky*4+kx)*32+ic
      int j = i - 8192;
      int n = j >> 9, k = j & 511;
      int kyx = k >> 5, ic = k & 31, ky = kyx >> 2, kx = kyx & 3;
      B2t[j] = f2b(w2[((n * 32 + ic) * 4 + ky) * 4 + kx]);
    } else if (i < 8192 + 32768 + 36864) { // conv3: [n=64][k=576], k=(ky*3+kx)*64+ic
      int j = i - 40960;
      int n = j / 576, k = j - n * 576;
      int ic = k & 63, kyx = k >> 6, ky = kyx / 3, kx = kyx % 3;
      B3t[j] = f2b(w3[((n * 64 + ic) * 3 + ky) * 3 + kx]);
    }
    return;
  }
  const float* src; u16* dst; int K, N, kt, nt, t;
  if (bid < 98)       { t = bid;       src = enc_lw; dst = Wt_enc;  K = 3136; N = 128; kt = t >> 1; nt = t & 1; }
  else if (bid < 146) { t = bid - 98;  src = proj_w; dst = Wt_proj; K = 384;  N = 512; kt = t >> 3; nt = t & 7; }
  else if (bid < 210) { t = bid - 146; src = pre_w;  dst = Wt_pre;  K = 512;  N = 512; kt = t >> 3; nt = t & 7; }
  else if (bid < 466) { t = bid - 210; int L = t >> 6; t &= 63;
                        src = aft_w + (size_t)L * 262144; dst = Wt_aft + (size_t)L * 262144;
                        K = 512; N = 512; kt = t >> 3; nt = t & 7; }
  else                { t = bid - 466; src = out_w;  dst = Wt_out;  K = 512;  N = 18;  kt = t;      nt = 0; }
  int k0 = kt * 64, n0 = nt * 64;
  #pragma unroll
  for (int it = 0; it < 16; it++) {
    int idx = it * 256 + threadIdx.x;
    int rr = idx >> 6, cc = idx & 63;
    float v = (n0 + cc < N) ? src[(size_t)(k0 + rr) * N + n0 + cc] : 0.f;
    T[cc][rr] = f2b(v);
  }
  __syncthreads();
  #pragma unroll
  for (int it = 0; it < 16; it++) {
    int idx = it * 256 + threadIdx.x;
    int rr = idx >> 6, cc = idx & 63;
    dst[(size_t)(n0 + rr) * K + k0 + cc] = T[rr][cc];
  }
}

// ---------------- conv1 MFMA: [4,84,84]f32 -> [400 pos][32 oc]bf16, k8 s4, ReLU -------
// Split-issue staging; VGPR capped to 128 (2 blocks/CU = 16 waves/CU).
__global__ __launch_bounds__(512, 2) void conv1_mfma(const float* __restrict__ states,
    const u16* __restrict__ B1t, const float* __restrict__ bias, u16* __restrict__ out) {
  __shared__ u16 lds[28224];            // [ic][84][84] bf16
  int fr = blockIdx.x;
  int b = fr >> 7, s = fr & 127;
  const float* in = states + (size_t)(b * Tq + s + 1) * 28224;
  int tid = threadIdx.x;
  float4 stg[14];
  #pragma unroll
  for (int it = 0; it < 14; it++) {
    int idx = tid + it * 512;
    if (idx < 7056) stg[it] = ((const float4*)in)[idx];
  }
  #pragma unroll
  for (int it = 0; it < 14; it++) {
    int idx = tid + it * 512;
    if (idx < 7056) {
      ushort4 uv;
      uv.x = f2b(stg[it].x); uv.y = f2b(stg[it].y);
      uv.z = f2b(stg[it].z); uv.w = f2b(stg[it].w);
      *(ushort4*)&lds[idx * 4] = uv;
    }
  }
  int lane = tid & 63, w = tid >> 6;
  int q = lane >> 4, r = lane & 15;
  short8v bfr[2][8];
  #pragma unroll
  for (int nt = 0; nt < 2; nt++)
    #pragma unroll
    for (int ks = 0; ks < 8; ks++)
      bfr[nt][ks] = *(const short8v*)(B1t + (nt * 16 + r) * 256 + ks * 32 + q * 8);
  __syncthreads();
  for (int mt = w; mt < 25; mt += 8) {
    int m = mt * 16 + r;
    int oy = m / 20, ox = m % 20;
    f32x4 acc0 = {0.f, 0.f, 0.f, 0.f}, acc1 = {0.f, 0.f, 0.f, 0.f};
    #pragma unroll
    for (int ks = 0; ks < 8; ks++) {
      int k0 = ks * 32 + q * 8;
      int ic = k0 >> 6, ky = (k0 >> 3) & 7;
      int ai = ic * 7056 + (oy * 4 + ky) * 84 + ox * 4;
      ushort4 lo = *(const ushort4*)&lds[ai];
      ushort4 hi = *(const ushort4*)&lds[ai + 4];
      short8v av;
      av[0] = (short)lo.x; av[1] = (short)lo.y; av[2] = (short)lo.z; av[3] = (short)lo.w;
      av[4] = (short)hi.x; av[5] = (short)hi.y; av[6] = (short)hi.z; av[7] = (short)hi.w;
      acc0 = __builtin_amdgcn_mfma_f32_16x16x32_bf16(av, bfr[0][ks], acc0, 0, 0, 0);
      acc1 = __builtin_amdgcn_mfma_f32_16x16x32_bf16(av, bfr[1][ks], acc1, 0, 0, 0);
    }
    #pragma unroll
    for (int reg = 0; reg < 4; reg++) {
      int pos = mt * 16 + q * 4 + reg;
      out[(size_t)fr * 12800 + pos * 32 + r]      = f2b(fmaxf(acc0[reg] + bias[r], 0.f));
      out[(size_t)fr * 12800 + pos * 32 + 16 + r] = f2b(fmaxf(acc1[reg] + bias[16 + r], 0.f));
    }
  }
}

// ---------------- fused conv2+conv3: o1 -> (LDS o2) -> x3b ----------------
// LDS 36KB; VGPR capped to 128 (4 blocks/CU).
__global__ __launch_bounds__(256, 4) void conv23_mfma(const u16* __restrict__ o1,
    const u16* __restrict__ B2t, const u16* __restrict__ B3t,
    const float* __restrict__ b2, const float* __restrict__ b3,
    u16* __restrict__ x3b) {
  __shared__ u16 o1l[12800];   // [400 pos][32 oc]
  __shared__ u16 o2l[5184];    // [81 pos][64 oc]
  int fr = blockIdx.x;
  int tid = threadIdx.x;
  const short8v* src = (const short8v*)(o1 + (size_t)fr * 12800);
  short8v* dst = (short8v*)o1l;
  #pragma unroll
  for (int it = 0; it < 7; it++) {
    int idx = tid + it * 256;
    if (idx < 1600) dst[idx] = src[idx];
  }
  int lane = tid & 63, w = tid >> 6;
  int q = lane >> 4, r = lane & 15;
  int n = w * 16 + r;
  short8v bfr2[16];
  #pragma unroll
  for (int ks = 0; ks < 16; ks++)
    bfr2[ks] = *(const short8v*)(B2t + n * 512 + ks * 32 + q * 8);
  __syncthreads();
  // ---- conv2: M=81, N=64, K=512 -> o2l ----
  float bn2 = b2[n];
  #pragma unroll
  for (int mt = 0; mt < 6; mt++) {
    int m = mt * 16 + r; if (m > 80) m = 80;
    int oy = m / 9, ox = m % 9;
    f32x4 acc = {0.f, 0.f, 0.f, 0.f};
    #pragma unroll
    for (int ks = 0; ks < 16; ks++) {
      int ky = ks >> 2, kx = ks & 3;
      int ai = ((oy * 2 + ky) * 20 + ox * 2 + kx) * 32 + q * 8;
      short8v av = *(const short8v*)&o1l[ai];
      acc = __builtin_amdgcn_mfma_f32_16x16x32_bf16(av, bfr2[ks], acc, 0, 0, 0);
    }
    #pragma unroll
    for (int reg = 0; reg < 4; reg++) {
      int pos = mt * 16 + q * 4 + reg;
      if (pos < 81)
        o2l[pos * 64 + n] = f2b(fmaxf(acc[reg] + bn2, 0.f));
    }
  }
  short8v bfr3[18];
  #pragma unroll
  for (int ks = 0; ks < 18; ks++)
    bfr3[ks] = *(const short8v*)(B3t + n * 576 + ks * 32 + q * 8);
  __syncthreads();
  // ---- conv3: M=49, N=64, K=576 -> x3b (reference flatten order) ----
  float bn3 = b3[n];
  #pragma unroll
  for (int mt = 0; mt < 4; mt++) {
    int m = mt * 16 + r; if (m > 48) m = 48;
    int oy = m / 7, ox = m % 7;
    f32x4 acc = {0.f, 0.f, 0.f, 0.f};
    #pragma unroll
    for (int ks = 0; ks < 18; ks++) {
      int kyx = ks >> 1;
      int ky = kyx / 3, kx = kyx % 3;
      int ic0 = (ks & 1) * 32 + q * 8;
      int ai = ((oy + ky) * 9 + ox + kx) * 64 + ic0;
      short8v av = *(const short8v*)&o2l[ai];
      acc = __builtin_amdgcn_mfma_f32_16x16x32_bf16(av, bfr3[ks], acc, 0, 0, 0);
    }
    #pragma unroll
    for (int reg = 0; reg < 4; reg++) {
      int pos = mt * 16 + q * 4 + reg;
      if (pos < 49)
        x3b[(size_t)fr * 3136 + n * 49 + pos] = f2b(fmaxf(acc[reg] + bn3, 0.f));
    }
  }
}

// ---------------- bf16 MFMA GEMM: C = epi(A @ Wt^T + bias), BK=128 ----------------
template<bool AF32, int EPI, bool STATS>
__global__ __launch_bounds__(256) void mgemm(const void* __restrict__ Av,
    const u16* __restrict__ Wt, const float* __restrict__ bias,
    const float* __restrict__ res, void* __restrict__ Cv,
    float2* __restrict__ part, int M, int K, int N, int ldc) {
  __shared__ u16 As[4][64][40];
  __shared__ u16 Bs[4][64][40];
  int tid = threadIdx.x;
  int bn = blockIdx.x * 64, bm = blockIdx.y * 64;
  int lane = tid & 63, w = tid >> 6;
  int q = lane >> 4, r = lane & 15;
  int wm = (w >> 1) * 32, wn = (w & 1) * 32;
  int am = tid >> 2, ak0 = (tid & 3) * 8;
  f32x4 acc[2][2] = {};
  for (int k0 = 0; k0 < K; k0 += 128) {
    #pragma unroll
    for (int st = 0; st < 4; st++) {
      int kk = k0 + st * 32 + ak0;
      if constexpr (AF32) {
        const float* A = (const float*)Av;
        const float* src = A + (size_t)(bm + am) * K + kk;
        float4 v0 = *(const float4*)src;
        float4 v1 = *(const float4*)(src + 4);
        ushort4 lo, hi;
        lo.x = f2b(v0.x); lo.y = f2b(v0.y); lo.z = f2b(v0.z); lo.w = f2b(v0.w);
        hi.x = f2b(v1.x); hi.y = f2b(v1.y); hi.z = f2b(v1.z); hi.w = f2b(v1.w);
        *(ushort4*)&As[st][am][ak0] = lo;
        *(ushort4*)&As[st][am][ak0 + 4] = hi;
      } else {
        *(short8v*)&As[st][am][ak0] =
            *(const short8v*)((const u16*)Av + (size_t)(bm + am) * K + kk);
      }
      *(short8v*)&Bs[st][am][ak0] = *(const short8v*)(Wt + (size_t)(bn + am) * K + kk);
    }
    __syncthreads();
    #pragma unroll
    for (int st = 0; st < 4; st++) {
      short8v a0 = *(const short8v*)&As[st][wm + r][q * 8];
      short8v a1 = *(const short8v*)&As[st][wm + 16 + r][q * 8];
      short8v b0 = *(const short8v*)&Bs[st][wn + r][q * 8];
      short8v b1 = *(const short8v*)&Bs[st][wn + 16 + r][q * 8];
      acc[0][0] = __builtin_amdgcn_mfma_f32_16x16x32_bf16(a0, b0, acc[0][0], 0, 0, 0);
      acc[0][1] = __builtin_amdgcn_mfma_f32_16x16x32_bf16(a0, b1, acc[0][1], 0, 0, 0);
      acc[1][0] = __builtin_amdgcn_mfma_f32_16x16x32_bf16(a1, b0, acc[1][0], 0, 0, 0);
      acc[1][1] = __builtin_amdgcn_mfma_f32_16x16x32_bf16(a1, b1, acc[1][1], 0, 0, 0);
    }
    __syncthreads();
  }
  float yv[2][2][4];
  #pragma unroll
  for (int ms = 0; ms < 2; ms++) {
    #pragma unroll
    for (int ns = 0; ns < 2; ns++) {
      #pragma unroll
      for (int reg = 0; reg < 4; reg++) {
        int m = bm + wm + ms * 16 + q * 4 + reg;
        int n = bn + wn + ns * 16 + r;
        if (n < N) {
          float v = acc[ms][ns][reg] + (bias ? bias[n] : 0.f);
          if (EPI == 0) { ((float*)Cv)[(size_t)m * ldc + n] = v; yv[ms][ns][reg] = v; }
          if (EPI == 2) ((u16*)Cv)[(size_t)m * ldc + n] = f2b(gelu_f(v));
          if (EPI == 3) {
            float o = gelu_f(v) + res[(size_t)m * ldc + n];
            ((float*)Cv)[(size_t)m * ldc + n] = o; yv[ms][ns][reg] = o;
          }
        }
      }
    }
  }
  if constexpr (STATS) {
    #pragma unroll
    for (int ms = 0; ms < 2; ms++) {
      #pragma unroll
      for (int reg = 0; reg < 4; reg++) {
        float s = yv[ms][0][reg] + yv[ms][1][reg];
        float s2 = yv[ms][0][reg] * yv[ms][0][reg] + yv[ms][1][reg] * yv[ms][1][reg];
        #pragma unroll
        for (int o = 1; o <= 8; o <<= 1) {
          s += __shfl_xor(s, o);
          s2 += __shfl_xor(s2, o);
        }
        if (r == 0) {
          int m = bm + wm + ms * 16 + q * 4 + reg;
          part[(size_t)(blockIdx.x * 2 + (w & 1)) * 1024 + m] = make_float2(s, s2);
        }
      }
    }
  }
}

// ---------------- enc GEMM split-K ----------------
__global__ __launch_bounds__(256) void enc_gemm(const u16* __restrict__ A,
    const u16* __restrict__ Wt, float* __restrict__ Cp) {
  __shared__ u16 As[64][40];
  __shared__ u16 Bs[64][40];
  int tid = threadIdx.x;
  int bn = blockIdx.x * 64, bm = blockIdx.y * 64, kc = blockIdx.z;
  int lane = tid & 63, w = tid >> 6;
  int q = lane >> 4, r = lane & 15;
  int wm = (w >> 1) * 32, wn = (w & 1) * 32;
  int am = tid >> 2, ak = (tid & 3) * 8;
  f32x4 acc[2][2] = {};
  int kend = kc * 448 + 448;
  for (int k0 = kc * 448; k0 < kend; k0 += 32) {
    *(short8v*)&As[am][ak] = *(const short8v*)(A + (size_t)(bm + am) * 3136 + k0 + ak);
    *(short8v*)&Bs[am][ak] = *(const short8v*)(Wt + (size_t)(bn + am) * 3136 + k0 + ak);
    __syncthreads();
    short8v a0 = *(const short8v*)&As[wm + r][q * 8];
    short8v a1 = *(const short8v*)&As[wm + 16 + r][q * 8];
    short8v b0 = *(const short8v*)&Bs[wn + r][q * 8];
    short8v b1 = *(const short8v*)&Bs[wn + 16 + r][q * 8];
    acc[0][0] = __builtin_amdgcn_mfma_f32_16x16x32_bf16(a0, b0, acc[0][0], 0, 0, 0);
    acc[0][1] = __builtin_amdgcn_mfma_f32_16x16x32_bf16(a0, b1, acc[0][1], 0, 0, 0);
    acc[1][0] = __builtin_amdgcn_mfma_f32_16x16x32_bf16(a1, b0, acc[1][0], 0, 0, 0);
    acc[1][1] = __builtin_amdgcn_mfma_f32_16x16x32_bf16(a1, b1, acc[1][1], 0, 0, 0);
    __syncthreads();
  }
  #pragma unroll
  for (int ms = 0; ms < 2; ms++)
    #pragma unroll
    for (int ns = 0; ns < 2; ns++)
      #pragma unroll
      for (int reg = 0; reg < 4; reg++) {
        int m = bm + wm + ms * 16 + q * 4 + reg;
        int n = bn + wn + ns * 16 + r;
        Cp[(size_t)(kc * 1024 + m) * 128 + n] = acc[ms][ns][reg];
      }
}

// ---------------- enc reduce + embeddings -> uin (bf16) ----------------
__global__ __launch_bounds__(256) void embedred_k(const float* __restrict__ Cp,
    const float* __restrict__ enc_lb, const int* __restrict__ actions,
    const float* __restrict__ rtgs, const float* __restrict__ act_emb,
    const float* __restrict__ ret_w, const float* __restrict__ ret_b,
    u16* __restrict__ uin) {
  int f = blockIdx.x;
  int b = f >> 7, s = f & 127;
  int e = threadIdx.x;
  if (e < 128) {
    float sum = enc_lb[e];
    #pragma unroll
    for (int kc = 0; kc < 7; kc++) sum += Cp[(size_t)(kc * 1024 + f) * 128 + e];
    uin[(size_t)f * 384 + e] = f2b(tanhf(sum));
    uin[(size_t)f * 384 + 256 + e] =
        f2b(tanhf(fmaf(rtgs[b * Tq + s], ret_w[e], ret_b[e])));
  } else {
    int ee = e - 128;
    int a = actions[b * Tq + s];
    uin[(size_t)f * 384 + 128 + ee] = f2b(tanhf(act_emb[a * NEq + ee]));
  }
}

// ---------------- S4 kernel gen: Ktb[layer][l][h] bf16 ----------------
__global__ __launch_bounds__(64) void s4k_gen(const float* __restrict__ log_dt,
    const float* __restrict__ A_re, const float* __restrict__ A_im,
    const float* __restrict__ C_re, const float* __restrict__ C_im,
    u16* __restrict__ Ktb) {
  __shared__ float con[64][129];
  int lh = blockIdx.x;
  int n = threadIdx.x;
  float dt = expf(log_dt[lh]);
  float ar = A_re[(size_t)lh * Nq + n], ai = A_im[(size_t)lh * Nq + n];
  float al = dt * ar, be = dt * ai;
  float er = expf(al);
  float wr = er * cosf(be), wi = er * sinf(be);
  float zr = wr - 1.0f, zi = wi;
  float den = 1.0f / (ar * ar + ai * ai);
  float tr = (zr * ar + zi * ai) * den, ti = (zi * ar - zr * ai) * den;
  float Cr = C_re[(size_t)lh * Nq + n], Ci = C_im[(size_t)lh * Nq + n];
  float cr = Cr * tr - Ci * ti, ci = Cr * ti + Ci * tr;
  float curr = 1.0f, curi = 0.0f;
  for (int l = 0; l < Sq; l++) {
    con[n][l] = cr * curr - ci * curi;
    float nr = curr * wr - curi * wi;
    curi = curr * wi + curi * wr;
    curr = nr;
  }
  __syncthreads();
  int layer = lh >> 9, h = lh & 511;
  #pragma unroll
  for (int li = n; li < Sq; li += 64) {
    float s = 0.f;
    for (int j = 0; j < 64; j++) s += con[j][li];
    Ktb[((size_t)layer * Sq + li) * Hq + h] = f2b(2.0f * s);
  }
}

// ---------------- fused LN + causal seq conv + gelu -> bf16 ----------------
__global__ __launch_bounds__(256) void sconv_fused(const float* __restrict__ y,
    const float2* __restrict__ part, const float* __restrict__ g,
    const float* __restrict__ bta, const u16* __restrict__ Kt,
    const float* __restrict__ D, u16* __restrict__ cact) {
  __shared__ u32 P[16][140];
  __shared__ u32 KL[16][132];
  __shared__ float2 statl[128];
  int hc = blockIdx.x, b = blockIdx.y;
  int t = threadIdx.x;
  int h0 = hc * 32;
  if (t < 128) {
    float s = 0.f, s2 = 0.f;
    #pragma unroll
    for (int pc = 0; pc < 16; pc++) {
      float2 pp = part[(size_t)pc * 1024 + b * Sq + t];
      s += pp.x; s2 += pp.y;
    }
    float mu = s * (1.f / Hq);
    float var = s2 * (1.f / Hq) - mu * mu;
    statl[t] = make_float2(mu, rsqrtf(var + 1e-5f));
  }
  if (t < 16) {
    #pragma unroll
    for (int i = 0; i < 8; i++) P[t][i] = 0;
  }
  #pragma unroll
  for (int it = 0; it < 8; it++) {
    int idx = it * 256 + t;
    int p = idx & 15, j = idx >> 4;
    KL[p][j] = *(const u32*)(Kt + (size_t)j * Hq + h0 + 2 * p);
  }
  __syncthreads();
  #pragma unroll
  for (int it = 0; it < 8; it++) {
    int idx = it * 256 + t;
    int p = idx & 15, s = idx >> 4;
    int row = b * Sq + s;
    float2 v = *(const float2*)(y + (size_t)row * Hq + h0 + 2 * p);
    float2 st = statl[s];
    float2 gg = *(const float2*)(g + h0 + 2 * p);
    float2 bb = *(const float2*)(bta + h0 + 2 * p);
    float r0 = (v.x - st.x) * st.y * gg.x + bb.x;
    float r1 = (v.y - st.x) * st.y * gg.y + bb.y;
    P[p][8 + s] = (u32)f2b(r0) | ((u32)f2b(r1) << 16);
  }
  __syncthreads();
  int p = t & 15, sg = t >> 4;
  int s0 = sg * 8;
  float acc0[8], acc1[8];
  float2 d2 = *(const float2*)(D + h0 + 2 * p);
  #pragma unroll
  for (int k = 0; k < 8; k++) {
    u32 rv = P[p][8 + s0 + k];
    acc0[k] = d2.x * b2f_lo(rv);
    acc1[k] = d2.y * b2f_hi(rv);
  }
  for (int jb = 0; jb <= sg; jb++) {
    int base = (sg - jb) * 8;
    u32 wv[16], kv[8];
    *(uint4*)&wv[0]  = *(const uint4*)&P[p][base];
    *(uint4*)&wv[4]  = *(const uint4*)&P[p][base + 4];
    *(uint4*)&wv[8]  = *(const uint4*)&P[p][base + 8];
    *(uint4*)&wv[12] = *(const uint4*)&P[p][base + 12];
    *(uint4*)&kv[0]  = *(const uint4*)&KL[p][jb * 8];
    *(uint4*)&kv[4]  = *(const uint4*)&KL[p][jb * 8 + 4];
    float wlo[16], whi[16], klo[8], khi[8];
    #pragma unroll
    for (int i = 0; i < 16; i++) { wlo[i] = b2f_lo(wv[i]); whi[i] = b2f_hi(wv[i]); }
    #pragma unroll
    for (int i = 0; i < 8; i++) { klo[i] = b2f_lo(kv[i]); khi[i] = b2f_hi(kv[i]); }
    #pragma unroll
    for (int jo = 0; jo < 8; jo++)
      #pragma unroll
      for (int k = 0; k < 8; k++) {
        acc0[k] = fmaf(klo[jo], wlo[8 + k - jo], acc0[k]);
        acc1[k] = fmaf(khi[jo], whi[8 + k - jo], acc1[k]);
      }
  }
  #pragma unroll
  for (int k = 0; k < 8; k++) {
    int s = s0 + k;
    u32 outv = (u32)f2b(gelu_f(acc0[k])) | ((u32)f2b(gelu_f(acc1[k])) << 16);
    *(u32*)(cact + ((size_t)(b * Sq + s)) * Hq + h0 + 2 * p) = outv;
  }
}

// ---------------- host ----------------
extern "C" void kernel_launch(void* const* d_in, const int* in_sizes, int n_in,
                              void* d_out, int out_size, void* d_ws, size_t ws_size,
                              hipStream_t stream) {
  const float* states  = (const float*)d_in[0];
  const int*   actions = (const int*)  d_in[1];
  const float* rtgs    = (const float*)d_in[2];
  const float* enc_w1  = (const float*)d_in[3];
  const float* enc_b1  = (const float*)d_in[4];
  const float* enc_w2  = (const float*)d_in[5];
  const float* enc_b2  = (const float*)d_in[6];
  const float* enc_w3  = (const float*)d_in[7];
  const float* enc_b3  = (const float*)d_in[8];
  const float* enc_lw  = (const float*)d_in[9];
  const float* enc_lb  = (const float*)d_in[10];
  const float* ret_w   = (const float*)d_in[11];
  const float* ret_b   = (const float*)d_in[12];
  const float* act_emb = (const float*)d_in[13];
  const float* proj_w  = (const float*)d_in[14];
  const float* proj_b  = (const float*)d_in[15];
  const float* pre_w   = (const float*)d_in[16];
  const float* pre_b   = (const float*)d_in[17];
  const float* ln_g    = (const float*)d_in[18];
  const float* ln_b    = (const float*)d_in[19];
  const float* log_dt  = (const float*)d_in[20];
  const float* A_re    = (const float*)d_in[21];
  const float* A_im    = (const float*)d_in[22];
  const float* C_re    = (const float*)d_in[23];
  const float* C_im    = (const float*)d_in[24];
  const float* Dp      = (const float*)d_in[25];
  const float* aft_w   = (const float*)d_in[26];
  const float* aft_b   = (const float*)d_in[27];
  const float* out_w   = (const float*)d_in[28];

  // workspace layout (u16 units), all regions 16B aligned
  u16* Wt_enc  = (u16*)d_ws;            // 401,408
  u16* Wt_proj = Wt_enc + 401408;       // 196,608
  u16* Wt_pre  = Wt_proj + 196608;      // 262,144
  u16* Wt_aft  = Wt_pre + 262144;       // 1,048,576
  u16* Wt_out  = Wt_aft + 1048576;      // 32,768
  u16* B1t = Wt_out + 32768;            // 8,192
  u16* B2t = B1t + 8192;                // 32,768
  u16* B3t = B2t + 32768;               // 36,864
  u16* o1  = B3t + 36864;               // 13,107,200
  u16* x3b = o1 + 13107200;             // 3,211,264
  u16* uin = x3b + 3211264;             // 393,216
  u16* uact = uin + 393216;             // 524,288
  u16* cact = uact + 524288;            // 524,288
  u16* Ktb  = cact + 524288;            // 262,144
  float* y    = (float*)(Ktb + 262144); // 524,288 f32
  float* Cp   = y + 524288;             // 917,504 f32 (7*1024*128)
  float2* part = (float2*)(Cp + 917504);// 16*1024 float2

  prep_k<<<778, 256, 0, stream>>>(enc_lw, proj_w, pre_w, aft_w, out_w,
                                  enc_w1, enc_w2, enc_w3,
                                  Wt_enc, Wt_proj, Wt_pre, Wt_aft, Wt_out,
                                  B1t, B2t, B3t);
  conv1_mfma<<<1024, 512, 0, stream>>>(states, B1t, enc_b1, o1);
  conv23_mfma<<<1024, 256, 0, stream>>>(o1, B2t, B3t, enc_b2, enc_b3, x3b);
  enc_gemm<<<dim3(2, 16, 7), 256, 0, stream>>>(x3b, Wt_enc, Cp);
  embedred_k<<<1024, 256, 0, stream>>>(Cp, enc_lb, actions, rtgs, act_emb,
                                       ret_w, ret_b, uin);
  mgemm<false, 2, false><<<dim3(8, 16), 256, 0, stream>>>(uin, Wt_proj, proj_b,
      nullptr, uact, nullptr, 1024, 384, 512, 512);
  mgemm<false, 0, true><<<dim3(8, 16), 256, 0, stream>>>(uact, Wt_pre, pre_b,
      nullptr, y, part, 1024, 512, 512, 512);
  s4k_gen<<<2048, 64, 0, stream>>>(log_dt, A_re, A_im, C_re, C_im, Ktb);

  for (int i = 0; i < NLq; i++) {
    sconv_fused<<<dim3(16, 8), 256, 0, stream>>>(y, part, ln_g + i * Hq,
                                                 ln_b + i * Hq,
                                                 Ktb + (size_t)i * Sq * Hq,
                                                 Dp + i * Hq, cact);
    mgemm<false, 3, true><<<dim3(8, 16), 256, 0, stream>>>(cact,
        Wt_aft + (size_t)i * Hq * Hq, aft_b + i * Hq, y, y, part,
        1024, 512, 512, 512);
  }
  mgemm<true, 0, false><<<dim3(1, 16), 256, 0, stream>>>(y, Wt_out, nullptr,
      nullptr, (float*)d_out, nullptr, 1024, 512, Vq, Vq);
}